// Round 1
// baseline (681.374 us; speedup 1.0000x reference)
//
#include <hip/hip_runtime.h>

// ChildSumTreeLSTMCell — fused bf16-MFMA implementation.
// N=65536 nodes, K=4 children, X=300, H=256.
//
// Pipeline:
//   prep_*  : repack weights fp32 -> bf16 fragment-major buffers in d_ws
//   k1_fpath: per 16 nodes: stage x,h_msgs (bf16 LDS), h_tild -> d_out[h-slot],
//             wf GEMM (LDS), uh GEMM + fused sigmoid*c_msgs -> c_tild -> d_out[c-slot]
//   k2_iou  : per 64 nodes: A=[x|h_tild] bf16 LDS, K=576 GEMM for (i,o,u) triples,
//             fused gate epilogue overwrites h,c in d_out.

typedef __attribute__((ext_vector_type(8))) short short8;
typedef __attribute__((ext_vector_type(4))) float f32x4;

#define NN 65536

__device__ __forceinline__ unsigned short f2bf(float f) {
  unsigned int u = __float_as_uint(f);
  u += 0x7FFFu + ((u >> 16) & 1u);   // round-to-nearest-even
  return (unsigned short)(u >> 16);
}

__device__ __forceinline__ f32x4 mfma16(short8 a, short8 b, f32x4 c) {
  return __builtin_amdgcn_mfma_f32_16x16x32_bf16(a, b, c, 0, 0, 0);
}

__device__ __forceinline__ float sigmoidf_(float v) {
  return 1.0f / (1.0f + __expf(-v));
}

// ---------------- weight prep ----------------
// B-frag layout: [kt][ct][lane][8] bf16; lane holds B[k = kt*32 + 8*(lane>>4) + j][col = ct*16 + (lane&15)]

__global__ void prep_wf(const float* __restrict__ Wf, unsigned short* __restrict__ B) {
  int idx = blockIdx.x * 256 + threadIdx.x;            // 10*16*64*8 = 81920
  if (idx >= 10*16*64*8) return;
  int j = idx & 7, lane = (idx >> 3) & 63, ct = (idx >> 9) & 15, kt = idx >> 13;
  int k = kt*32 + ((lane >> 4) << 3) + j;
  int col = ct*16 + (lane & 15);
  float v = (k < 300) ? Wf[col*300 + k] : 0.0f;
  B[idx] = f2bf(v);
}

__global__ void prep_uf(const float* __restrict__ Uf, unsigned short* __restrict__ B) {
  int idx = blockIdx.x * 256 + threadIdx.x;            // 8*16*64*8 = 65536
  if (idx >= 8*16*64*8) return;
  int j = idx & 7, lane = (idx >> 3) & 63, ct = (idx >> 9) & 15, kt = idx >> 13;
  int k = kt*32 + ((lane >> 4) << 3) + j;
  int col = ct*16 + (lane & 15);
  B[idx] = f2bf(Uf[col*256 + k]);
}

// iou columns permuted: col-tile ct covers gate (ct%3), cols (ct/3)*16..+15.
// B rows 0..299 = W_iou^T, 300..319 = 0, 320..575 = U_iou^T.
__global__ void prep_iou(const float* __restrict__ Wiou, const float* __restrict__ Uiou,
                         unsigned short* __restrict__ B) {
  int idx = blockIdx.x * 256 + threadIdx.x;            // 18*48*64*8 = 442368
  if (idx >= 18*48*64*8) return;
  int j = idx & 7, lane = (idx >> 3) & 63;
  int rest = idx >> 9;
  int ct = rest % 48, kt = rest / 48;
  int k = kt*32 + ((lane >> 4) << 3) + j;
  int gate = ct % 3, cb = (ct/3) * 16;
  int g = gate*256 + cb + (lane & 15);
  float v;
  if (k < 320) v = (k < 300) ? Wiou[g*300 + k] : 0.0f;
  else         v = Uiou[g*256 + (k - 320)];
  B[idx] = f2bf(v);
}

// ---------------- kernel 1: f-path ----------------
__global__ __launch_bounds__(256, 2) void k1_fpath(
    const float* __restrict__ x, const float* __restrict__ h_msgs,
    const float* __restrict__ c_msgs,
    const float* __restrict__ bWf, const float* __restrict__ bUf,
    const unsigned short* __restrict__ Bwf, const unsigned short* __restrict__ Buf,
    float* __restrict__ h_tild_out, float* __restrict__ c_tild_out) {
  __shared__ alignas(16) unsigned short Xt[16*328];   // 16 nodes x 320 (pad stride 328)
  __shared__ alignas(16) unsigned short Hm[64*264];   // row = n*4+k, 256 cols (stride 264)
  __shared__ float wfs[16*260];                       // wf fp32, stride 260
  const int tid = threadIdx.x;
  const int n0 = blockIdx.x * 16;

  // stage x -> bf16 (zero-pad cols 300..319)
  for (int i = tid; i < 16*320; i += 256) {
    int r = i / 320, c = i - r*320;
    float v = (c < 300) ? x[(size_t)(n0+r)*300 + c] : 0.0f;
    Xt[r*328 + c] = f2bf(v);
  }
  // stage h_msgs -> bf16, h_tild = sum_k -> global (fp32, h-slot of d_out)
  for (int i = tid; i < 16*256; i += 256) {
    int r = i >> 8, c = i & 255;
    const float* hp = h_msgs + (size_t)(n0+r)*1024 + c;
    float s = 0.0f;
#pragma unroll
    for (int k = 0; k < 4; ++k) {
      float v = hp[k*256];
      s += v;
      Hm[(r*4+k)*264 + c] = f2bf(v);
    }
    h_tild_out[(size_t)(n0+r)*256 + c] = s;
  }
  __syncthreads();

  const int wave = tid >> 6, lane = tid & 63;
  const int lrow = lane & 15, lgrp = lane >> 4;
  const f32x4 fzero = {0.0f, 0.0f, 0.0f, 0.0f};

  // ---- wf GEMM: [16 x 320] x [320 x 256]; wave w -> cols 64w..64w+63
  f32x4 acc[4];
#pragma unroll
  for (int ct = 0; ct < 4; ++ct) acc[ct] = fzero;
  for (int ks = 0; ks < 10; ++ks) {
    short8 a = *(const short8*)&Xt[lrow*328 + ks*32 + lgrp*8];
    const unsigned short* bp = Bwf + ((ks*16 + wave*4)*64 + lane)*8;
#pragma unroll
    for (int ct = 0; ct < 4; ++ct) {
      short8 b = *(const short8*)(bp + ct*512);
      acc[ct] = mfma16(a, b, acc[ct]);
    }
  }
#pragma unroll
  for (int ct = 0; ct < 4; ++ct) {
    int col = wave*64 + ct*16 + lrow;
    float bias = bWf[col];
#pragma unroll
    for (int r = 0; r < 4; ++r)
      wfs[(lgrp*4 + r)*260 + col] = acc[ct][r] + bias;
  }
  __syncthreads();

  // ---- uh GEMM: [64 x 256] x [256 x 256]; wave w -> cols 64w.., all 4 row-tiles
  f32x4 acc2[4][4];
#pragma unroll
  for (int rt = 0; rt < 4; ++rt)
#pragma unroll
    for (int ct = 0; ct < 4; ++ct) acc2[rt][ct] = fzero;
  for (int ks = 0; ks < 8; ++ks) {
    const unsigned short* bp = Buf + ((ks*16 + wave*4)*64 + lane)*8;
    short8 b[4];
#pragma unroll
    for (int ct = 0; ct < 4; ++ct) b[ct] = *(const short8*)(bp + ct*512);
#pragma unroll
    for (int rt = 0; rt < 4; ++rt) {
      short8 a = *(const short8*)&Hm[(rt*16 + lrow)*264 + ks*32 + lgrp*8];
#pragma unroll
      for (int ct = 0; ct < 4; ++ct) acc2[rt][ct] = mfma16(a, b[ct], acc2[rt][ct]);
    }
  }
  // fused epilogue: f = sigmoid(wf + uh + bUf); c_tild = sum_k f * c_msgs
#pragma unroll
  for (int rt = 0; rt < 4; ++rt) {
#pragma unroll
    for (int ct = 0; ct < 4; ++ct) {
      int col = wave*64 + ct*16 + lrow;
      int nl = rt*4 + lgrp;                 // local node; r = child index k
      float wfv = wfs[nl*260 + col];
      float bu = bUf[col];
      float ctl = 0.0f;
#pragma unroll
      for (int r = 0; r < 4; ++r) {
        float uh = acc2[rt][ct][r] + wfv + bu;
        float fg = sigmoidf_(uh);
        float cm = c_msgs[(size_t)(n0+nl)*1024 + r*256 + col];
        ctl += fg * cm;
      }
      c_tild_out[(size_t)(n0+nl)*256 + col] = ctl;
    }
  }
}

// ---------------- kernel 2: iou-path ----------------
__global__ __launch_bounds__(256, 2) void k2_iou(
    const float* __restrict__ x, const float* __restrict__ h_tild,
    const float* __restrict__ b_iou, const float* __restrict__ b_Uiou,
    const unsigned short* __restrict__ Biou,
    float* __restrict__ out_h, float* __restrict__ out_c) {
  __shared__ alignas(16) unsigned short Ac[64*584];   // 64 nodes x 576 (pad stride 584)
  const int tid = threadIdx.x;
  const int n0 = blockIdx.x * 64;

  for (int i = tid; i < 64*320; i += 256) {
    int r = i / 320, c = i - r*320;
    float v = (c < 300) ? x[(size_t)(n0+r)*300 + c] : 0.0f;
    Ac[r*584 + c] = f2bf(v);
  }
  for (int i = tid; i < 64*256; i += 256) {
    int r = i >> 8, c = i & 255;
    Ac[r*584 + 320 + c] = f2bf(h_tild[(size_t)(n0+r)*256 + c]);
  }
  __syncthreads();

  const int wave = tid >> 6, lane = tid & 63;
  const int lrow = lane & 15, lgrp = lane >> 4;
  const f32x4 fzero = {0.0f, 0.0f, 0.0f, 0.0f};

#pragma unroll 1
  for (int j = 0; j < 4; ++j) {              // 4 (i,o,u) col-triples per wave
    int ct0 = wave*12 + j*3;
    f32x4 aI[4], aO[4], aU[4];
#pragma unroll
    for (int rt = 0; rt < 4; ++rt) { aI[rt] = fzero; aO[rt] = fzero; aU[rt] = fzero; }
    for (int ks = 0; ks < 18; ++ks) {
      const unsigned short* bp = Biou + ((size_t)(ks*48 + ct0)*64 + lane)*8;
      short8 bI8 = *(const short8*)bp;
      short8 bO8 = *(const short8*)(bp + 512);
      short8 bU8 = *(const short8*)(bp + 1024);
#pragma unroll
      for (int rt = 0; rt < 4; ++rt) {
        short8 a = *(const short8*)&Ac[(rt*16 + lrow)*584 + ks*32 + lgrp*8];
        aI[rt] = mfma16(a, bI8, aI[rt]);
        aO[rt] = mfma16(a, bO8, aO[rt]);
        aU[rt] = mfma16(a, bU8, aU[rt]);
      }
    }
    int col = (wave*4 + j)*16 + lrow;
    float bI = b_iou[col]       + b_Uiou[col];
    float bO = b_iou[256 + col] + b_Uiou[256 + col];
    float bU = b_iou[512 + col] + b_Uiou[512 + col];
#pragma unroll
    for (int rt = 0; rt < 4; ++rt) {
#pragma unroll
      for (int r = 0; r < 4; ++r) {
        int row = rt*16 + lgrp*4 + r;
        size_t n = (size_t)(n0 + row);
        float iv = sigmoidf_(aI[rt][r] + bI);
        float ov = sigmoidf_(aO[rt][r] + bO);
        float uv = tanhf(aU[rt][r] + bU);
        float ctl = out_c[n*256 + col];      // c_tild (same lane re-writes below)
        float cv = iv*uv + ctl;
        float hv = ov * tanhf(cv);
        out_h[n*256 + col] = hv;
        out_c[n*256 + col] = cv;
      }
    }
  }
}

extern "C" void kernel_launch(void* const* d_in, const int* in_sizes, int n_in,
                              void* d_out, int out_size, void* d_ws, size_t ws_size,
                              hipStream_t stream) {
  const float* x      = (const float*)d_in[0];
  const float* h_msgs = (const float*)d_in[1];
  const float* c_msgs = (const float*)d_in[2];
  const float* W_iou  = (const float*)d_in[3];
  const float* b_iou  = (const float*)d_in[4];
  const float* U_iou  = (const float*)d_in[5];
  const float* b_Uiou = (const float*)d_in[6];
  const float* W_f    = (const float*)d_in[7];
  const float* b_Wf   = (const float*)d_in[8];
  const float* U_f    = (const float*)d_in[9];
  const float* b_Uf   = (const float*)d_in[10];

  unsigned short* Bwf  = (unsigned short*)d_ws;          // 81920 bf16
  unsigned short* Buf  = Bwf + 10*16*64*8;               // 65536 bf16
  unsigned short* Biou = Buf + 8*16*64*8;                // 442368 bf16

  float* h_slot = (float*)d_out;                         // h_tild, then h
  float* c_slot = h_slot + (size_t)NN*256;               // c_tild, then c

  prep_wf <<<(10*16*64*8)/256, 256, 0, stream>>>(W_f, Bwf);
  prep_uf <<<(8*16*64*8)/256,  256, 0, stream>>>(U_f, Buf);
  prep_iou<<<(18*48*64*8)/256, 256, 0, stream>>>(W_iou, U_iou, Biou);

  k1_fpath<<<NN/16, 256, 0, stream>>>(x, h_msgs, c_msgs, b_Wf, b_Uf, Bwf, Buf, h_slot, c_slot);
  k2_iou  <<<NN/64, 256, 0, stream>>>(x, h_slot, b_iou, b_Uiou, Biou, h_slot, c_slot);
}

// Round 2
// 365.521 us; speedup vs baseline: 1.8641x; 1.8641x over previous
//
#include <hip/hip_runtime.h>

// ChildSumTreeLSTMCell — fused bf16-MFMA, round 2.
// Changes vs R1: 512-thread blocks (2x occupancy), float4 staging everywhere,
// LDS-transpose epilogues so ALL global IO is 128B-line-friendly, B prefetch.

typedef __attribute__((ext_vector_type(8))) short short8;
typedef __attribute__((ext_vector_type(4))) float f32x4;
typedef __attribute__((ext_vector_type(4))) unsigned short us4;
typedef __attribute__((ext_vector_type(4))) unsigned int u32x4;

#define NN 65536

__device__ __forceinline__ unsigned short f2bf(float f) {
  unsigned int u = __float_as_uint(f);
  u += 0x7FFFu + ((u >> 16) & 1u);   // RNE
  return (unsigned short)(u >> 16);
}
__device__ __forceinline__ float bf2f(unsigned short s) {
  return __uint_as_float(((unsigned int)s) << 16);
}
__device__ __forceinline__ f32x4 mfma16(short8 a, short8 b, f32x4 c) {
  return __builtin_amdgcn_mfma_f32_16x16x32_bf16(a, b, c, 0, 0, 0);
}
__device__ __forceinline__ float sigmoidf_(float v) {
  return 1.0f / (1.0f + __expf(-v));
}
__device__ __forceinline__ float ftanh(float v) {
  return 1.0f - 2.0f / (__expf(2.0f * v) + 1.0f);   // safe at +-inf
}

// ---------------- weight prep ----------------
// B-frag layout: [kt][ct][lane][8]; lane holds B[k=kt*32+8*(lane>>4)+j][col=ct*16+(lane&15)]

__global__ void prep_wf(const float* __restrict__ Wf, unsigned short* __restrict__ B) {
  int idx = blockIdx.x * 256 + threadIdx.x;            // 10*16*64*8
  if (idx >= 10*16*64*8) return;
  int j = idx & 7, lane = (idx >> 3) & 63, ct = (idx >> 9) & 15, kt = idx >> 13;
  int k = kt*32 + ((lane >> 4) << 3) + j;
  int col = ct*16 + (lane & 15);
  float v = (k < 300) ? Wf[col*300 + k] : 0.0f;
  B[idx] = f2bf(v);
}

__global__ void prep_uf(const float* __restrict__ Uf, unsigned short* __restrict__ B) {
  int idx = blockIdx.x * 256 + threadIdx.x;            // 8*16*64*8
  if (idx >= 8*16*64*8) return;
  int j = idx & 7, lane = (idx >> 3) & 63, ct = (idx >> 9) & 15, kt = idx >> 13;
  int k = kt*32 + ((lane >> 4) << 3) + j;
  int col = ct*16 + (lane & 15);
  B[idx] = f2bf(Uf[col*256 + k]);
}

// iou: ct in [0,48): gate = ct%3, colblock = ct/3. K rows: 0..299 Wiou, 300..319 zero, 320..575 Uiou.
__global__ void prep_iou(const float* __restrict__ Wiou, const float* __restrict__ Uiou,
                         unsigned short* __restrict__ B) {
  int idx = blockIdx.x * 256 + threadIdx.x;            // 18*48*64*8
  if (idx >= 18*48*64*8) return;
  int j = idx & 7, lane = (idx >> 3) & 63;
  int rest = idx >> 9;
  int ct = rest % 48, kt = rest / 48;
  int k = kt*32 + ((lane >> 4) << 3) + j;
  int gate = ct % 3, cb = (ct/3) * 16;
  int g = gate*256 + cb + (lane & 15);
  float v;
  if (k < 320) v = (k < 300) ? Wiou[g*300 + k] : 0.0f;
  else         v = Uiou[g*256 + (k - 320)];
  B[idx] = f2bf(v);
}

// ---------------- kernel 1: f-path ----------------
// 16 nodes/block, 512 threads (8 waves). LDS ~60.9KB -> 2 blocks/CU, 16 waves/CU.
__global__ __launch_bounds__(512, 4) void k1_fpath(
    const float* __restrict__ x, const float* __restrict__ h_msgs,
    const float* __restrict__ c_msgs,
    const float* __restrict__ bWf, const float* __restrict__ bUf,
    const unsigned short* __restrict__ Bwf, const unsigned short* __restrict__ Buf,
    float* __restrict__ h_tild_out, float* __restrict__ c_tild_out) {
  __shared__ alignas(16) unsigned short Xt[16*328];   // x bf16, stride 328
  __shared__ alignas(16) unsigned short Hm[64*264];   // h_msgs bf16; reused as f-gates
  __shared__ float wfs[16*260];                       // wf fp32
  const int tid = threadIdx.x;
  const int n0 = blockIdx.x * 16;

  // stage x (float4 loads, bf16x4 LDS stores)
  for (int i = tid; i < 16*80; i += 512) {
    int r = i / 80, c4 = i - r*80;
    f32x4 v = {0.0f, 0.0f, 0.0f, 0.0f};
    if (c4 < 75) v = *(const f32x4*)&x[(size_t)(n0+r)*300 + c4*4];
    us4 o;
#pragma unroll
    for (int e = 0; e < 4; ++e) o[e] = f2bf(v[e]);
    *(us4*)&Xt[r*328 + c4*4] = o;
  }
  // stage h_msgs (float4) + h_tild sum -> global float4
  for (int i = tid; i < 16*64; i += 512) {
    int n = i >> 6, c4 = i & 63;
    const float* hp = h_msgs + (size_t)(n0+n)*1024 + c4*4;
    f32x4 s = {0.0f, 0.0f, 0.0f, 0.0f};
#pragma unroll
    for (int k = 0; k < 4; ++k) {
      f32x4 v = *(const f32x4*)(hp + k*256);
      us4 o;
#pragma unroll
      for (int e = 0; e < 4; ++e) { s[e] += v[e]; o[e] = f2bf(v[e]); }
      *(us4*)&Hm[(n*4+k)*264 + c4*4] = o;
    }
    *(f32x4*)&h_tild_out[(size_t)(n0+n)*256 + c4*4] = s;
  }
  __syncthreads();

  const int wave = tid >> 6, lane = tid & 63;
  const int lrow = lane & 15, lgrp = lane >> 4;
  const f32x4 fzero = {0.0f, 0.0f, 0.0f, 0.0f};

  // ---- wf GEMM: [16x320]x[320x256]; wave w -> cols 32w..32w+31 (2 ct)
  f32x4 acc[2] = {fzero, fzero};
#pragma unroll
  for (int ks = 0; ks < 10; ++ks) {
    short8 a = *(const short8*)&Xt[lrow*328 + ks*32 + lgrp*8];
    const unsigned short* bp = Bwf + ((ks*16 + wave*2)*64 + lane)*8;
    acc[0] = mfma16(a, *(const short8*)bp,         acc[0]);
    acc[1] = mfma16(a, *(const short8*)(bp + 512), acc[1]);
  }
#pragma unroll
  for (int ct = 0; ct < 2; ++ct) {
    int col = wave*32 + ct*16 + lrow;
    float bias = bWf[col];
#pragma unroll
    for (int r = 0; r < 4; ++r)
      wfs[(lgrp*4 + r)*260 + col] = acc[ct][r] + bias;
  }
  __syncthreads();

  // ---- uh GEMM: [64x256]x[256x256]; wave w -> cols 32w.., all 4 row-tiles
  f32x4 a2[4][2];
#pragma unroll
  for (int rt = 0; rt < 4; ++rt) { a2[rt][0] = fzero; a2[rt][1] = fzero; }
  {
    const unsigned short* bp = Buf + (wave*2*64 + lane)*8;
    short8 b0 = *(const short8*)bp;
    short8 b1 = *(const short8*)(bp + 512);
#pragma unroll 1
    for (int ks = 0; ks < 8; ++ks) {
      short8 n0b, n1b;
      if (ks < 7) {
        const unsigned short* np = Buf + (((ks+1)*16 + wave*2)*64 + lane)*8;
        n0b = *(const short8*)np;
        n1b = *(const short8*)(np + 512);
      }
#pragma unroll
      for (int rt = 0; rt < 4; ++rt) {
        short8 a = *(const short8*)&Hm[(rt*16 + lrow)*264 + ks*32 + lgrp*8];
        a2[rt][0] = mfma16(a, b0, a2[rt][0]);
        a2[rt][1] = mfma16(a, b1, a2[rt][1]);
      }
      b0 = n0b; b1 = n1b;
    }
  }
  __syncthreads();          // everyone done reading Hm

  // f = sigmoid(wf + uh + bUf) -> Fg (reuse Hm), bf16
#pragma unroll
  for (int ct = 0; ct < 2; ++ct) {
    int col = wave*32 + ct*16 + lrow;
    float bu = bUf[col];
#pragma unroll
    for (int rt = 0; rt < 4; ++rt) {
      float wfv = wfs[(rt*4 + lgrp)*260 + col];
#pragma unroll
      for (int r = 0; r < 4; ++r) {
        float fg = sigmoidf_(a2[rt][ct][r] + wfv + bu);
        Hm[(rt*16 + lgrp*4 + r)*264 + col] = f2bf(fg);
      }
    }
  }
  __syncthreads();

  // c_tild = sum_k f*c_msgs  (float4 coalesced global IO)
  for (int i = tid; i < 16*64; i += 512) {
    int n = i >> 6, c4 = i & 63;
    f32x4 acc4 = {0.0f, 0.0f, 0.0f, 0.0f};
#pragma unroll
    for (int k = 0; k < 4; ++k) {
      f32x4 cm = *(const f32x4*)&c_msgs[((size_t)(n0+n)*4 + k)*256 + c4*4];
      us4 fb = *(const us4*)&Hm[(n*4+k)*264 + c4*4];
#pragma unroll
      for (int e = 0; e < 4; ++e) acc4[e] += bf2f(fb[e]) * cm[e];
    }
    *(f32x4*)&c_tild_out[(size_t)(n0+n)*256 + c4*4] = acc4;
  }
}

// ---------------- kernel 2: iou-path ----------------
// 64 nodes/block, 512 threads (8 waves). LDS 74.75KB -> 2 blocks/CU.
__global__ __launch_bounds__(512, 4) void k2_iou(
    const float* __restrict__ x, const float* __restrict__ h_tild,
    const float* __restrict__ b_iou, const float* __restrict__ b_Uiou,
    const unsigned short* __restrict__ Biou,
    float* __restrict__ out_h, float* __restrict__ out_c) {
  __shared__ alignas(16) unsigned short Ac[64*584];   // A=[x|h_tild] bf16; reused as gate buf
  unsigned int* IUO = (unsigned int*)Ac;              // [64][264] u32 (bf16 iu | bf16 o)
  const int tid = threadIdx.x;
  const int n0 = blockIdx.x * 64;

  for (int i = tid; i < 64*80; i += 512) {
    int r = i / 80, c4 = i - r*80;
    f32x4 v = {0.0f, 0.0f, 0.0f, 0.0f};
    if (c4 < 75) v = *(const f32x4*)&x[(size_t)(n0+r)*300 + c4*4];
    us4 o;
#pragma unroll
    for (int e = 0; e < 4; ++e) o[e] = f2bf(v[e]);
    *(us4*)&Ac[r*584 + c4*4] = o;
  }
  for (int i = tid; i < 64*64; i += 512) {
    int r = i >> 6, c4 = i & 63;
    f32x4 v = *(const f32x4*)&h_tild[(size_t)(n0+r)*256 + c4*4];
    us4 o;
#pragma unroll
    for (int e = 0; e < 4; ++e) o[e] = f2bf(v[e]);
    *(us4*)&Ac[r*584 + 320 + c4*4] = o;
  }
  __syncthreads();

  const int wave = tid >> 6, lane = tid & 63;
  const int lrow = lane & 15, lgrp = lane >> 4;
  const f32x4 fzero = {0.0f, 0.0f, 0.0f, 0.0f};

  // wave w, triple jj -> gate cols (w*2+jj)*16 + lrow for i/o/u
  auto do_triple = [&](int jj, unsigned int* pk) {
    int ct0 = wave*6 + jj*3;
    int col = (wave*2 + jj)*16 + lrow;
    float bI = b_iou[col]       + b_Uiou[col];
    float bO = b_iou[256 + col] + b_Uiou[256 + col];
    float bU = b_iou[512 + col] + b_Uiou[512 + col];
    f32x4 aI[4], aO[4], aU[4];
#pragma unroll
    for (int rt = 0; rt < 4; ++rt) { aI[rt] = fzero; aO[rt] = fzero; aU[rt] = fzero; }
    const unsigned short* bp = Biou + ((size_t)ct0*64 + lane)*8;
    short8 bI8 = *(const short8*)bp;
    short8 bO8 = *(const short8*)(bp + 512);
    short8 bU8 = *(const short8*)(bp + 1024);
#pragma unroll 1
    for (int ks = 0; ks < 18; ++ks) {
      short8 nI = bI8, nO = bO8, nU = bU8;
      if (ks < 17) {
        const unsigned short* np = Biou + (((size_t)(ks+1)*48 + ct0)*64 + lane)*8;
        nI = *(const short8*)np;
        nO = *(const short8*)(np + 512);
        nU = *(const short8*)(np + 1024);
      }
#pragma unroll
      for (int rt = 0; rt < 4; ++rt) {
        short8 a = *(const short8*)&Ac[(rt*16 + lrow)*584 + ks*32 + lgrp*8];
        aI[rt] = mfma16(a, bI8, aI[rt]);
        aO[rt] = mfma16(a, bO8, aO[rt]);
        aU[rt] = mfma16(a, bU8, aU[rt]);
      }
      bI8 = nI; bO8 = nO; bU8 = nU;
    }
#pragma unroll
    for (int rt = 0; rt < 4; ++rt) {
#pragma unroll
      for (int r = 0; r < 4; ++r) {
        float iv = sigmoidf_(aI[rt][r] + bI);
        float ov = sigmoidf_(aO[rt][r] + bO);
        float uv = ftanh(aU[rt][r] + bU);
        float iu = iv * uv;
        pk[rt*4 + r] = (unsigned int)f2bf(iu) | ((unsigned int)f2bf(ov) << 16);
      }
    }
  };

  unsigned int pk0[16], pk1[16];
  do_triple(0, pk0);
  do_triple(1, pk1);
  __syncthreads();          // all waves done reading Ac

  // scatter packed gates into LDS (2-way-free bank pattern)
#pragma unroll
  for (int rt = 0; rt < 4; ++rt)
#pragma unroll
    for (int r = 0; r < 4; ++r) {
      int row = rt*16 + lgrp*4 + r;
      IUO[row*264 + wave*32 + lrow]      = pk0[rt*4 + r];
      IUO[row*264 + wave*32 + 16 + lrow] = pk1[rt*4 + r];
    }
  __syncthreads();

  // writer: c = iu + c_tild; h = o*tanh(c)  (all float4 coalesced)
  for (int i = tid; i < 64*64; i += 512) {
    int n = i >> 6, c4 = i & 63;
    u32x4 pk = *(const u32x4*)&IUO[n*264 + c4*4];
    size_t base = (size_t)(n0+n)*256 + c4*4;
    f32x4 ctl = *(const f32x4*)&out_c[base];
    f32x4 hv, cv;
#pragma unroll
    for (int e = 0; e < 4; ++e) {
      float iu = bf2f((unsigned short)(pk[e] & 0xFFFFu));
      float ov = bf2f((unsigned short)(pk[e] >> 16));
      float c  = iu + ctl[e];
      cv[e] = c;
      hv[e] = ov * ftanh(c);
    }
    *(f32x4*)&out_h[base] = hv;
    *(f32x4*)&out_c[base] = cv;
  }
}

extern "C" void kernel_launch(void* const* d_in, const int* in_sizes, int n_in,
                              void* d_out, int out_size, void* d_ws, size_t ws_size,
                              hipStream_t stream) {
  const float* x      = (const float*)d_in[0];
  const float* h_msgs = (const float*)d_in[1];
  const float* c_msgs = (const float*)d_in[2];
  const float* W_iou  = (const float*)d_in[3];
  const float* b_iou  = (const float*)d_in[4];
  const float* U_iou  = (const float*)d_in[5];
  const float* b_Uiou = (const float*)d_in[6];
  const float* W_f    = (const float*)d_in[7];
  const float* b_Wf   = (const float*)d_in[8];
  const float* U_f    = (const float*)d_in[9];
  const float* b_Uf   = (const float*)d_in[10];

  unsigned short* Bwf  = (unsigned short*)d_ws;          // 81920 bf16
  unsigned short* Buf  = Bwf + 10*16*64*8;               // 65536 bf16
  unsigned short* Biou = Buf + 8*16*64*8;                // 442368 bf16

  float* h_slot = (float*)d_out;                         // h_tild, then h
  float* c_slot = h_slot + (size_t)NN*256;               // c_tild, then c

  prep_wf <<<(10*16*64*8)/256, 256, 0, stream>>>(W_f, Bwf);
  prep_uf <<<(8*16*64*8)/256,  256, 0, stream>>>(U_f, Buf);
  prep_iou<<<(18*48*64*8)/256, 256, 0, stream>>>(W_iou, U_iou, Biou);

  k1_fpath<<<NN/16, 512, 0, stream>>>(x, h_msgs, c_msgs, b_Wf, b_Uf, Bwf, Buf, h_slot, c_slot);
  k2_iou  <<<NN/64, 512, 0, stream>>>(x, h_slot, b_iou, b_Uiou, Biou, h_slot, c_slot);
}

// Round 3
// 335.533 us; speedup vs baseline: 2.0307x; 1.0894x over previous
//
#include <hip/hip_runtime.h>

// ChildSumTreeLSTMCell — round 3: single fused kernel.
// 32 nodes/block, 512 threads (8 waves), 2 blocks/CU.
// Per block: stage x -> A[32][584] bf16; 4 chunks of 8 nodes:
//   {stage h_msgs->Hm + h_tild->A + prefetch c_msgs -> regs;
//    uh GEMM; f=sigmoid(wf+uh+b) -> Hm; c_tild (regs)}
// wf GEMM once -> wfs LDS (bf16). Then K=576 iou GEMM over A,
// gate epilogue -> IUO LDS transpose -> coalesced h,c writes.

typedef __attribute__((ext_vector_type(8))) short short8;
typedef __attribute__((ext_vector_type(4))) float f32x4;
typedef __attribute__((ext_vector_type(4))) unsigned short us4;
typedef __attribute__((ext_vector_type(4))) unsigned int u32x4;

#define NN 65536

__device__ __forceinline__ unsigned short f2bf(float f) {
  unsigned int u = __float_as_uint(f);
  u += 0x7FFFu + ((u >> 16) & 1u);   // RNE
  return (unsigned short)(u >> 16);
}
__device__ __forceinline__ float bf2f(unsigned short s) {
  return __uint_as_float(((unsigned int)s) << 16);
}
__device__ __forceinline__ f32x4 mfma16(short8 a, short8 b, f32x4 c) {
  return __builtin_amdgcn_mfma_f32_16x16x32_bf16(a, b, c, 0, 0, 0);
}
__device__ __forceinline__ float sigmoidf_(float v) { return 1.0f / (1.0f + __expf(-v)); }
__device__ __forceinline__ float ftanh(float v) { return 1.0f - 2.0f / (__expf(2.0f * v) + 1.0f); }

// ---------------- weight prep (one kernel) ----------------
// frag layout: [kt][ct][lane][8]; lane holds B[k=kt*32+8*(lane>>4)+j][col=ct*16+(lane&15)]
// Bwf 81920 @0, Buf 65536 @81920, Biou 442368 @147456 (ushort units).
__global__ void prep_all(const float* __restrict__ Wf, const float* __restrict__ Uf,
                         const float* __restrict__ Wiou, const float* __restrict__ Uiou,
                         unsigned short* __restrict__ ws) {
  int idx = blockIdx.x * 256 + threadIdx.x;          // 589824 total
  if (idx < 81920) {                                  // Bwf [10][16][64][8]
    int j = idx & 7, lane = (idx >> 3) & 63, ct = (idx >> 9) & 15, kt = idx >> 13;
    int k = kt*32 + ((lane >> 4) << 3) + j, col = ct*16 + (lane & 15);
    ws[idx] = f2bf(k < 300 ? Wf[col*300 + k] : 0.0f);
  } else if (idx < 147456) {                          // Buf [8][16][64][8]
    int i = idx - 81920;
    int j = i & 7, lane = (i >> 3) & 63, ct = (i >> 9) & 15, kt = i >> 13;
    int k = kt*32 + ((lane >> 4) << 3) + j, col = ct*16 + (lane & 15);
    ws[idx] = f2bf(Uf[col*256 + k]);
  } else {                                            // Biou [18][48][64][8]
    int i = idx - 147456;
    int j = i & 7, lane = (i >> 3) & 63;
    int rest = i >> 9, ct = rest % 48, kt = rest / 48;
    int k = kt*32 + ((lane >> 4) << 3) + j;
    int g = (ct % 3)*256 + (ct/3)*16 + (lane & 15);
    float v = (k < 320) ? (k < 300 ? Wiou[g*300 + k] : 0.0f) : Uiou[g*256 + (k - 320)];
    ws[idx] = f2bf(v);
  }
}

// ---------------- fused cell ----------------
__global__ __launch_bounds__(512, 4) void fused_cell(
    const float* __restrict__ x, const float* __restrict__ h_msgs,
    const float* __restrict__ c_msgs,
    const float* __restrict__ b_iou, const float* __restrict__ b_Uiou,
    const float* __restrict__ bWf, const float* __restrict__ bUf,
    const unsigned short* __restrict__ Bwf, const unsigned short* __restrict__ Buf,
    const unsigned short* __restrict__ Biou,
    float* __restrict__ out_h, float* __restrict__ out_c) {
  __shared__ alignas(16) char smem[71168];
  unsigned short* Axh = (unsigned short*)smem;            // [32][584]  37376 B
  unsigned short* Hm  = (unsigned short*)(smem + 37376);  // [32][264]  16896 B
  unsigned short* wfs = (unsigned short*)(smem + 54272);  // [32][264]  16896 B
  unsigned int*   IUO = (unsigned int*)(smem + 37376);    // [32][260]  33280 B (overlays Hm+wfs)

  const int tid = threadIdx.x;
  const int n0 = blockIdx.x * 32;
  const int wave = tid >> 6, lane = tid & 63;
  const int lrow = lane & 15, lgrp = lane >> 4;
  const int nl = wave;                 // node-in-chunk for row-mapped loops
  const f32x4 fz = {0.0f, 0.0f, 0.0f, 0.0f};

  // ---- stage x -> Axh cols 0..319 (zero-pad 300..319)
  for (int i = tid; i < 32*80; i += 512) {
    int r = i / 80, c4 = i - r*80;
    f32x4 v = fz;
    if (c4 < 75) v = *(const f32x4*)&x[(size_t)(n0 + r)*300 + c4*4];
    us4 o;
#pragma unroll
    for (int e = 0; e < 4; ++e) o[e] = f2bf(v[e]);
    *(us4*)&Axh[r*584 + c4*4] = o;
  }

  f32x4 ct_acc[4];
  f32x4 cmv[4];

  auto stage_h = [&](int chunk) {
    int node = n0 + chunk*8 + nl;
    const float* hp = h_msgs + (size_t)node*1024 + lane*4;
    f32x4 s = fz;
#pragma unroll
    for (int k = 0; k < 4; ++k) {
      f32x4 v = *(const f32x4*)(hp + k*256);
      us4 o;
#pragma unroll
      for (int e = 0; e < 4; ++e) { s[e] += v[e]; o[e] = f2bf(v[e]); }
      *(us4*)&Hm[(nl*4 + k)*264 + lane*4] = o;
    }
    us4 ht;
#pragma unroll
    for (int e = 0; e < 4; ++e) ht[e] = f2bf(s[e]);
    *(us4*)&Axh[(chunk*8 + nl)*584 + 320 + lane*4] = ht;
    const float* cp = c_msgs + (size_t)node*1024 + lane*4;   // prefetch (used 2 phases later)
#pragma unroll
    for (int k = 0; k < 4; ++k) cmv[k] = *(const f32x4*)(cp + k*256);
  };

  auto uh_gemm = [&](f32x4 a2[2][2]) {
#pragma unroll 2
    for (int ks = 0; ks < 8; ++ks) {
      const unsigned short* bp = Buf + ((ks*16 + wave*2)*64 + lane)*8;
      short8 b0 = *(const short8*)bp;
      short8 b1 = *(const short8*)(bp + 512);
#pragma unroll
      for (int rt = 0; rt < 2; ++rt) {
        short8 a = *(const short8*)&Hm[(rt*16 + lrow)*264 + ks*32 + lgrp*8];
        a2[rt][0] = mfma16(a, b0, a2[rt][0]);
        a2[rt][1] = mfma16(a, b1, a2[rt][1]);
      }
    }
  };

  auto fgates = [&](int chunk, f32x4 a2[2][2]) {
#pragma unroll
    for (int ct = 0; ct < 2; ++ct) {
      int col = wave*32 + ct*16 + lrow;
      float bu = bUf[col];
#pragma unroll
      for (int rt = 0; rt < 2; ++rt) {
        float wfv = bf2f(wfs[(chunk*8 + rt*4 + lgrp)*264 + col]);
#pragma unroll
        for (int r = 0; r < 4; ++r) {
          float fg = sigmoidf_(a2[rt][ct][r] + wfv + bu);
          Hm[(rt*16 + lgrp*4 + r)*264 + col] = f2bf(fg);
        }
      }
    }
  };

  auto ctild = [&](int chunk) {
    f32x4 a = fz;
#pragma unroll
    for (int k = 0; k < 4; ++k) {
      us4 fb = *(const us4*)&Hm[(nl*4 + k)*264 + lane*4];
#pragma unroll
      for (int e = 0; e < 4; ++e) a[e] += bf2f(fb[e]) * cmv[k][e];
    }
    ct_acc[chunk] = a;
  };

  // ---- chunk 0 staging
  stage_h(0);
  __syncthreads();

  // ---- wf GEMM: [32 x 320] x [320 x 256] -> wfs (bf16, +bias)
  {
    f32x4 w00 = fz, w01 = fz, w10 = fz, w11 = fz;
#pragma unroll 2
    for (int ks = 0; ks < 10; ++ks) {
      const unsigned short* bp = Bwf + ((ks*16 + wave*2)*64 + lane)*8;
      short8 b0 = *(const short8*)bp;
      short8 b1 = *(const short8*)(bp + 512);
      short8 a0 = *(const short8*)&Axh[lrow*584 + ks*32 + lgrp*8];
      short8 a1 = *(const short8*)&Axh[(16 + lrow)*584 + ks*32 + lgrp*8];
      w00 = mfma16(a0, b0, w00); w01 = mfma16(a0, b1, w01);
      w10 = mfma16(a1, b0, w10); w11 = mfma16(a1, b1, w11);
    }
#pragma unroll
    for (int ct = 0; ct < 2; ++ct) {
      int col = wave*32 + ct*16 + lrow;
      float bias = bWf[col];
      f32x4 v0 = ct ? w01 : w00, v1 = ct ? w11 : w10;
#pragma unroll
      for (int r = 0; r < 4; ++r) {
        wfs[(lgrp*4 + r)*264 + col]      = f2bf(v0[r] + bias);
        wfs[(16 + lgrp*4 + r)*264 + col] = f2bf(v1[r] + bias);
      }
    }
  }

  // ---- chunks (fully unrolled: ct_acc/cmv must be statically indexed)
#pragma unroll
  for (int chunk = 0; chunk < 4; ++chunk) {
    if (chunk > 0) {
      __syncthreads();          // ctild(chunk-1) done reading Hm
      stage_h(chunk);
      __syncthreads();
    }
    f32x4 a2[2][2] = {{fz, fz}, {fz, fz}};
    uh_gemm(a2);
    __syncthreads();            // Hm(h) reads done; wfs visible (chunk 0)
    fgates(chunk, a2);
    __syncthreads();
    ctild(chunk);
  }
  __syncthreads();              // all Hm/wfs reads done -> IUO may overwrite

  // ---- iou GEMM: [32 x 576] x [576 x 768]; wave owns 2 col-blocks x 3 gates
  f32x4 aI[2][2], aO[2][2], aU[2][2];
#pragma unroll
  for (int rt = 0; rt < 2; ++rt)
#pragma unroll
    for (int cb = 0; cb < 2; ++cb) { aI[rt][cb] = fz; aO[rt][cb] = fz; aU[rt][cb] = fz; }
#pragma unroll 2
  for (int ks = 0; ks < 18; ++ks) {
    const unsigned short* bp = Biou + ((size_t)(ks*48 + wave*6)*64 + lane)*8;
    short8 bi0 = *(const short8*)(bp);
    short8 bo0 = *(const short8*)(bp + 512);
    short8 bu0 = *(const short8*)(bp + 1024);
    short8 bi1 = *(const short8*)(bp + 1536);
    short8 bo1 = *(const short8*)(bp + 2048);
    short8 bu1 = *(const short8*)(bp + 2560);
#pragma unroll
    for (int rt = 0; rt < 2; ++rt) {
      short8 a = *(const short8*)&Axh[(rt*16 + lrow)*584 + ks*32 + lgrp*8];
      aI[rt][0] = mfma16(a, bi0, aI[rt][0]);
      aO[rt][0] = mfma16(a, bo0, aO[rt][0]);
      aU[rt][0] = mfma16(a, bu0, aU[rt][0]);
      aI[rt][1] = mfma16(a, bi1, aI[rt][1]);
      aO[rt][1] = mfma16(a, bo1, aO[rt][1]);
      aU[rt][1] = mfma16(a, bu1, aU[rt][1]);
    }
  }
  // gate epilogue -> IUO (packed bf16 iu | bf16 o)
#pragma unroll
  for (int cb = 0; cb < 2; ++cb) {
    int col = (wave*2 + cb)*16 + lrow;
    float bI = b_iou[col]       + b_Uiou[col];
    float bO = b_iou[256 + col] + b_Uiou[256 + col];
    float bU = b_iou[512 + col] + b_Uiou[512 + col];
#pragma unroll
    for (int rt = 0; rt < 2; ++rt)
#pragma unroll
      for (int r = 0; r < 4; ++r) {
        float iv = sigmoidf_(aI[rt][cb][r] + bI);
        float ov = sigmoidf_(aO[rt][cb][r] + bO);
        float uv = ftanh(aU[rt][cb][r] + bU);
        IUO[(rt*16 + lgrp*4 + r)*260 + col] =
            (unsigned int)f2bf(iv * uv) | ((unsigned int)f2bf(ov) << 16);
      }
  }
  __syncthreads();

  // ---- final coalesced write: c = iu + c_tild; h = o*tanh(c)
#pragma unroll
  for (int chunk = 0; chunk < 4; ++chunk) {
    int nb = chunk*8 + nl;
    size_t base = (size_t)(n0 + nb)*256 + lane*4;
    u32x4 pk = *(const u32x4*)&IUO[nb*260 + lane*4];
    f32x4 hv, cv;
#pragma unroll
    for (int e = 0; e < 4; ++e) {
      float iu = bf2f((unsigned short)(pk[e] & 0xFFFFu));
      float ov = bf2f((unsigned short)(pk[e] >> 16));
      float c  = iu + ct_acc[chunk][e];
      cv[e] = c;
      hv[e] = ov * ftanh(c);
    }
    *(f32x4*)&out_h[base] = hv;
    *(f32x4*)&out_c[base] = cv;
  }
}

extern "C" void kernel_launch(void* const* d_in, const int* in_sizes, int n_in,
                              void* d_out, int out_size, void* d_ws, size_t ws_size,
                              hipStream_t stream) {
  const float* x      = (const float*)d_in[0];
  const float* h_msgs = (const float*)d_in[1];
  const float* c_msgs = (const float*)d_in[2];
  const float* W_iou  = (const float*)d_in[3];
  const float* b_iou  = (const float*)d_in[4];
  const float* U_iou  = (const float*)d_in[5];
  const float* b_Uiou = (const float*)d_in[6];
  const float* W_f    = (const float*)d_in[7];
  const float* b_Wf   = (const float*)d_in[8];
  const float* U_f    = (const float*)d_in[9];
  const float* b_Uf   = (const float*)d_in[10];

  unsigned short* ws   = (unsigned short*)d_ws;
  unsigned short* Bwf  = ws;                    // [10][16][64][8]
  unsigned short* Buf  = ws + 81920;            // [8][16][64][8]
  unsigned short* Biou = ws + 147456;           // [18][48][64][8]

  float* h_slot = (float*)d_out;
  float* c_slot = h_slot + (size_t)NN*256;

  prep_all<<<2304, 256, 0, stream>>>(W_f, U_f, W_iou, U_iou, ws);
  fused_cell<<<NN/32, 512, 0, stream>>>(x, h_msgs, c_msgs, b_iou, b_Uiou,
                                        b_Wf, b_Uf, Bwf, Buf, Biou, h_slot, c_slot);
}